// Round 16
// baseline (1367.833 us; speedup 1.0000x reference)
//
#include <hip/hip_runtime.h>
#include <cstdint>

// ---- bf16 pack/unpack helpers (RNE) ----
__device__ inline unsigned int bfpack2(float a, float b) {
  unsigned int ua = __float_as_uint(a), ub = __float_as_uint(b);
  ua += 0x7FFFu + ((ua >> 16) & 1u);
  ub += 0x7FFFu + ((ub >> 16) & 1u);
  return (ua >> 16) | (ub & 0xFFFF0000u);
}
__device__ inline float bflo(unsigned int u) { return __uint_as_float(u << 16); }
__device__ inline float bfhi(unsigned int u) { return __uint_as_float(u & 0xFFFF0000u); }

// ---------------- degree histograms ----------------
__global__ __launch_bounds__(256) void pre_kernel(const int* __restrict__ src,
                                                  const int* __restrict__ dst,
                                                  int* __restrict__ deg,
                                                  int* __restrict__ deg2, int nE) {
  int e = blockIdx.x * 256 + threadIdx.x;
  if (e < nE) {
    atomicAdd(&deg[dst[e]], 1);
    atomicAdd(&deg2[src[e]], 1);
  }
}

// ---------------- scan stage A (dual; deg gets 8-pad rounding) ----------------
__global__ __launch_bounds__(256) void scanA_kernel(const int* __restrict__ deg,
                                                    const int* __restrict__ deg2,
                                                    int* __restrict__ rp,
                                                    int* __restrict__ rp2,
                                                    int* __restrict__ part,
                                                    int* __restrict__ part2,
                                                    int n, int nb) {
  __shared__ int sh[256];
  int b = blockIdx.x, t = threadIdx.x;
  const int* d = (b < nb) ? deg : deg2;
  int* r = (b < nb) ? rp : rp2;
  int* p = (b < nb) ? part : part2;
  int pad = (b < nb) ? 1 : 0;
  int bb = (b < nb) ? b : b - nb;
  int base = bb * 1024 + t * 4;
  int v0 = (base + 0 < n) ? d[base + 0] : 0;
  int v1 = (base + 1 < n) ? d[base + 1] : 0;
  int v2 = (base + 2 < n) ? d[base + 2] : 0;
  int v3 = (base + 3 < n) ? d[base + 3] : 0;
  if (pad) {
    v0 = (v0 + 7) & ~7; v1 = (v1 + 7) & ~7;
    v2 = (v2 + 7) & ~7; v3 = (v3 + 7) & ~7;
  }
  int ts = v0 + v1 + v2 + v3;
  sh[t] = ts;
  __syncthreads();
  for (int off = 1; off < 256; off <<= 1) {
    int x = (t >= off) ? sh[t - off] : 0;
    __syncthreads();
    sh[t] += x;
    __syncthreads();
  }
  int excl = sh[t] - ts;
  if (t == 255) p[bb] = sh[255];
  if (base + 0 < n) r[base + 0] = excl;
  if (base + 1 < n) r[base + 1] = excl + v0;
  if (base + 2 < n) r[base + 2] = excl + v0 + v1;
  if (base + 3 < n) r[base + 3] = excl + v0 + v1 + v2;
}

__global__ void scanB_kernel(int* part, int* part2, int* rp, int* rp2, int nb, int n) {
  if (threadIdx.x == 0) {
    int* p = (blockIdx.x == 0) ? part : part2;
    int* r = (blockIdx.x == 0) ? rp : rp2;
    int run = 0;
    for (int i = 0; i < nb; ++i) { int v = p[i]; p[i] = run; run += v; }
    r[n] = run;
  }
}

__global__ __launch_bounds__(256) void scanC_kernel(int* __restrict__ rp,
                                                    int* __restrict__ rp2,
                                                    const int* __restrict__ part,
                                                    const int* __restrict__ part2,
                                                    int* __restrict__ cursor,
                                                    int* __restrict__ cursor2,
                                                    const int* __restrict__ deg,
                                                    float* __restrict__ dinv, int n) {
  int i = blockIdx.x * 256 + threadIdx.x;
  if (i < n) {
    int v = rp[i] + part[i >> 10];
    rp[i] = v;
    cursor[i] = v;
    dinv[i] = rsqrtf((float)deg[i] + 1.0f);
  } else if (i < 2 * n) {
    int j = i - n;
    int v = rp2[j] + part2[j >> 10];
    rp2[j] = v;
    cursor2[j] = v;
  }
}

// ---------------- place + pad fused ----------------
// swp entry: (wgt as sign-less bf16, 15b) << 17 | src (17b).
// SC=true: also packs ea row to bf16 and scatters to eah[p2] inline.
template <bool SC>
__global__ __launch_bounds__(256) void placepad_kernel(const int* __restrict__ src,
                                                       const int* __restrict__ dst,
                                                       const int* __restrict__ batch,
                                                       const float* __restrict__ dinv,
                                                       const float* __restrict__ ea,
                                                       int* __restrict__ cursor,
                                                       int* __restrict__ cursor2,
                                                       unsigned int* __restrict__ swp,
                                                       unsigned int* __restrict__ epk,
                                                       int* __restrict__ pos2,
                                                       unsigned int* __restrict__ eah,
                                                       const int* __restrict__ rp,
                                                       const int* __restrict__ deg,
                                                       int nE, int nN) {
  int t = blockIdx.x * 256 + threadIdx.x;
  if (t < nE) {
    int s = src[t];
    int d = dst[t];
    int p1 = atomicAdd(&cursor[d], 1);
    unsigned int fb = __float_as_uint(dinv[s] * dinv[d]);
    fb += 0x7FFFu + ((fb >> 16) & 1u);
    swp[p1] = ((fb >> 16) << 17) | (unsigned int)s;
    int g = batch[s];
    int p2 = atomicAdd(&cursor2[s], 1);
    epk[p2] = ((unsigned int)g << 21) | (unsigned int)t;
    if (SC) {
      const float4* p = reinterpret_cast<const float4*>(ea + (size_t)t * 16);
      float4 a = p[0], b = p[1], c = p[2], dd = p[3];
      uint4 o0, o1;
      o0.x = bfpack2(a.x, a.y); o0.y = bfpack2(a.z, a.w);
      o0.z = bfpack2(b.x, b.y); o0.w = bfpack2(b.z, b.w);
      o1.x = bfpack2(c.x, c.y); o1.y = bfpack2(c.z, c.w);
      o1.z = bfpack2(dd.x, dd.y); o1.w = bfpack2(dd.z, dd.w);
      uint4* dp = reinterpret_cast<uint4*>(eah + (size_t)p2 * 8);
      dp[0] = o0;
      dp[1] = o1;
    } else {
      pos2[t] = p2;
    }
  } else if (t < nE + nN) {
    int i = t - nE;
    int b = rp[i] + deg[i], e = rp[i + 1];
    for (int k = b; k < e; ++k) swp[k] = (unsigned int)i;  // wgt bits 0
  } else if (t < nE + nN + 32) {
    int k = t - nE - nN;
    swp[rp[nN] + k] = 0u;
  }
}

// ---------------- dense GEMM: hpk2[8][N][8] = pack_bf16(act(A) @ W), slice-major ----------------
template <bool FUSED>
__global__ __launch_bounds__(256) void gemm128_kernel(const float* __restrict__ A,
                                                      const float* __restrict__ W,
                                                      const float* __restrict__ bs,
                                                      const float* __restrict__ bq,
                                                      const float* __restrict__ gm,
                                                      const float* __restrict__ bt,
                                                      float invN,
                                                      unsigned int* __restrict__ hpk2,
                                                      int nrows) {
  extern __shared__ float lds[];
  float* Ws = lds;                      // 128*128
  float* xs = lds + 128 * 128;          // 16*128
  float* scs = xs + 16 * 128;           // 128
  float* shs = scs + 128;               // 128
  const int t = threadIdx.x;
  for (int i = t; i < (128 * 128) / 4; i += 256)
    reinterpret_cast<float4*>(Ws)[i] = reinterpret_cast<const float4*>(W)[i];
  if (FUSED && t < 128) {
    float mu = bs[t] * invN;
    float var = bq[t] * invN - mu * mu;
    float sc = gm[t] * rsqrtf(var + 1e-5f);
    scs[t] = sc;
    shs[t] = bt[t] - mu * sc;
  }
  const int wave = t >> 6, lane = t & 63;
  const size_t sbase = (size_t)(lane >> 3) * (size_t)nrows * 8 + (lane & 7);
  for (int rb = blockIdx.x * 16; rb < nrows; rb += gridDim.x * 16) {
    int nr = min(16, nrows - rb);
    __syncthreads();
    for (int i = t; i < nr * 32; i += 256) {
      float4 v = reinterpret_cast<const float4*>(A + (size_t)rb * 128)[i];
      if (FUSED) {
        float4 sc4 = reinterpret_cast<const float4*>(scs)[i & 31];
        float4 sh4 = reinterpret_cast<const float4*>(shs)[i & 31];
        v.x = fmaxf(fmaf(v.x, sc4.x, sh4.x), 0.f);
        v.y = fmaxf(fmaf(v.y, sc4.y, sh4.y), 0.f);
        v.z = fmaxf(fmaf(v.z, sc4.z, sh4.z), 0.f);
        v.w = fmaxf(fmaf(v.w, sc4.w, sh4.w), 0.f);
      }
      reinterpret_cast<float4*>(xs)[i] = v;
    }
    __syncthreads();
    float acc[4][2] = {{0.f, 0.f}, {0.f, 0.f}, {0.f, 0.f}, {0.f, 0.f}};
    const float* xw = xs + wave * 4 * 128;
#pragma unroll 4
    for (int k = 0; k < 128; ++k) {
      float w0 = Ws[k * 128 + lane];
      float w1 = Ws[k * 128 + 64 + lane];
#pragma unroll
      for (int r = 0; r < 4; ++r) {
        float a = xw[r * 128 + k];
        acc[r][0] = fmaf(a, w0, acc[r][0]);
        acc[r][1] = fmaf(a, w1, acc[r][1]);
      }
    }
#pragma unroll
    for (int r = 0; r < 4; ++r) {
      int row = rb + wave * 4 + r;
      if (row < nrows)
        hpk2[sbase + (size_t)row * 8] = bfpack2(acc[r][0], acc[r][1]);
    }
  }
}

// ---------------- SpMM body (XCD channel-sliced, two nodes per wave) ----------------
__device__ __forceinline__ void spmm_body(const unsigned int* __restrict__ hpk2,
                                          const float* __restrict__ dinv,
                                          const int* __restrict__ rp,
                                          const unsigned int* __restrict__ swp,
                                          const float* __restrict__ bias,
                                          float* __restrict__ outp,
                                          float* __restrict__ bnsum,
                                          float* __restrict__ bnsq, int nN, int eb) {
  const int lane = threadIdx.x & 63;
  const int ch = lane & 7;
  const int es = lane >> 3;
  const int bid = (int)blockIdx.x - eb;
  const int slice = bid & 7;
  const unsigned int* hs = hpk2 + (size_t)slice * (size_t)nN * 8;
  const int cb = slice * 8;
  const int wib = (bid >> 3) * 4 + (int)(threadIdx.x >> 6);
  const int nws = (((int)gridDim.x - eb) >> 3) * 4;
  float b0 = bias[cb + ch], b1 = bias[64 + cb + ch];
  float s0 = 0.f, s1 = 0.f, q0 = 0.f, q1 = 0.f;
  const int half = (nN + 1) >> 1;

#define SPMM_CHUNK(J, ACC0, ACC1)                                         \
  {                                                                       \
    unsigned int v_ = __builtin_nontemporal_load(swp + (J) + es);         \
    unsigned int pp_ = hs[(size_t)(v_ & 0x1FFFFu) * 8 + ch];              \
    float ww_ = __uint_as_float((v_ & 0xFFFE0000u) >> 1);                 \
    ACC0 = fmaf(ww_, bflo(pp_), ACC0);                                    \
    ACC1 = fmaf(ww_, bfhi(pp_), ACC1);                                    \
  }

  for (int p = wib; p < half; p += nws) {
    const int n0 = p;
    const int n1 = p + half;
    const bool has1 = n1 < nN;
    int j0 = rp[n0];
    const int end0 = rp[n0 + 1];
    int j1 = 0, end1 = 0;
    if (has1) { j1 = rp[n1]; end1 = rp[n1 + 1]; }
    float a00 = 0.f, a01 = 0.f, b00 = 0.f, b01 = 0.f;
    float a10 = 0.f, a11 = 0.f, b10 = 0.f, b11 = 0.f;
    while (j0 + 8 < end0 && j1 + 8 < end1) {
      SPMM_CHUNK(j0, a00, a01);
      SPMM_CHUNK(j0 + 8, b00, b01);
      SPMM_CHUNK(j1, a10, a11);
      SPMM_CHUNK(j1 + 8, b10, b11);
      j0 += 16; j1 += 16;
    }
    while (j0 + 8 < end0) {
      SPMM_CHUNK(j0, a00, a01);
      SPMM_CHUNK(j0 + 8, b00, b01);
      j0 += 16;
    }
    if (j0 < end0) SPMM_CHUNK(j0, a00, a01);
    while (j1 + 8 < end1) {
      SPMM_CHUNK(j1, a10, a11);
      SPMM_CHUNK(j1 + 8, b10, b11);
      j1 += 16;
    }
    if (j1 < end1) SPMM_CHUNK(j1, a10, a11);

    a00 += b00; a01 += b01;
    a10 += b10; a11 += b11;
    a00 += __shfl_xor(a00, 8);  a01 += __shfl_xor(a01, 8);
    a10 += __shfl_xor(a10, 8);  a11 += __shfl_xor(a11, 8);
    a00 += __shfl_xor(a00, 16); a01 += __shfl_xor(a01, 16);
    a10 += __shfl_xor(a10, 16); a11 += __shfl_xor(a11, 16);
    a00 += __shfl_xor(a00, 32); a01 += __shfl_xor(a01, 32);
    a10 += __shfl_xor(a10, 32); a11 += __shfl_xor(a11, 32);
    if (es == 0) {
      {
        float dn = dinv[n0];
        float sw = dn * dn;
        unsigned int pn = hs[(size_t)n0 * 8 + ch];
        float o0 = fmaf(bflo(pn), sw, a00) + b0;
        float o1 = fmaf(bfhi(pn), sw, a01) + b1;
        __builtin_nontemporal_store(o0, &outp[(size_t)n0 * 128 + cb + ch]);
        __builtin_nontemporal_store(o1, &outp[(size_t)n0 * 128 + 64 + cb + ch]);
        s0 += o0; s1 += o1;
        q0 = fmaf(o0, o0, q0); q1 = fmaf(o1, o1, q1);
      }
      if (has1) {
        float dn = dinv[n1];
        float sw = dn * dn;
        unsigned int pn = hs[(size_t)n1 * 8 + ch];
        float o0 = fmaf(bflo(pn), sw, a10) + b0;
        float o1 = fmaf(bfhi(pn), sw, a11) + b1;
        __builtin_nontemporal_store(o0, &outp[(size_t)n1 * 128 + cb + ch]);
        __builtin_nontemporal_store(o1, &outp[(size_t)n1 * 128 + 64 + cb + ch]);
        s0 += o0; s1 += o1;
        q0 = fmaf(o0, o0, q0); q1 = fmaf(o1, o1, q1);
      }
    }
  }
#undef SPMM_CHUNK
  if (es == 0) {
    atomicAdd(&bnsum[cb + ch], s0);
    atomicAdd(&bnsum[64 + cb + ch], s1);
    atomicAdd(&bnsq[cb + ch], q0);
    atomicAdd(&bnsq[64 + cb + ch], q1);
  }
}

// ---------------- edge MLP body: STREAM graph-sorted bf16 rows, run-length regs ----------------
__device__ __forceinline__ void edge_body(const unsigned int* __restrict__ eah,
                                          const unsigned int* __restrict__ epk,
                                          const float* __restrict__ We1,
                                          const float* __restrict__ be1,
                                          float* __restrict__ esum,
                                          float* __restrict__ ecnt,
                                          int eoff, int eend, int chunk) {
  const int lane = threadIdx.x & 63;
  const int wid = ((int)blockIdx.x * 256 + (int)threadIdx.x) >> 6;
  int beg = eoff + wid * chunk;
  if (beg >= eend) return;
  int end = min(eend, beg + chunk);
  float w0[16], w1[16];
#pragma unroll
  for (int k = 0; k < 16; ++k) {
    w0[k] = We1[k * 128 + lane];
    w1[k] = We1[k * 128 + 64 + lane];
  }
  float b0 = be1[lane], b1 = be1[64 + lane];
  int cur = -1;
  float a0 = 0.f, a1 = 0.f, cnt = 0.f;
  const uint4* rowp = reinterpret_cast<const uint4*>(eah + (size_t)beg * 8);
  uint4 q0 = rowp[0], q1 = rowp[1];
  int g = (int)(epk[beg] >> 21);
  for (int j = beg; j < end; ++j) {
    uint4 n0, n1;
    int ng = g;
    if (j + 1 < end) {
      const uint4* np = reinterpret_cast<const uint4*>(eah + (size_t)(j + 1) * 8);
      n0 = np[0];
      n1 = np[1];
      ng = (int)(epk[j + 1] >> 21);
    }
    if (g != cur) {
      if (cur >= 0) {
        atomicAdd(&esum[cur * 128 + lane], a0);
        atomicAdd(&esum[cur * 128 + 64 + lane], a1);
        if (lane == 0) atomicAdd(&ecnt[cur], cnt);
      }
      cur = g; a0 = 0.f; a1 = 0.f; cnt = 0.f;
    }
    float u0 = b0, u1 = b1;
    float f;
    f = bflo(q0.x); u0 = fmaf(f, w0[0], u0);  u1 = fmaf(f, w1[0], u1);
    f = bfhi(q0.x); u0 = fmaf(f, w0[1], u0);  u1 = fmaf(f, w1[1], u1);
    f = bflo(q0.y); u0 = fmaf(f, w0[2], u0);  u1 = fmaf(f, w1[2], u1);
    f = bfhi(q0.y); u0 = fmaf(f, w0[3], u0);  u1 = fmaf(f, w1[3], u1);
    f = bflo(q0.z); u0 = fmaf(f, w0[4], u0);  u1 = fmaf(f, w1[4], u1);
    f = bfhi(q0.z); u0 = fmaf(f, w0[5], u0);  u1 = fmaf(f, w1[5], u1);
    f = bflo(q0.w); u0 = fmaf(f, w0[6], u0);  u1 = fmaf(f, w1[6], u1);
    f = bfhi(q0.w); u0 = fmaf(f, w0[7], u0);  u1 = fmaf(f, w1[7], u1);
    f = bflo(q1.x); u0 = fmaf(f, w0[8], u0);  u1 = fmaf(f, w1[8], u1);
    f = bfhi(q1.x); u0 = fmaf(f, w0[9], u0);  u1 = fmaf(f, w1[9], u1);
    f = bflo(q1.y); u0 = fmaf(f, w0[10], u0); u1 = fmaf(f, w1[10], u1);
    f = bfhi(q1.y); u0 = fmaf(f, w0[11], u0); u1 = fmaf(f, w1[11], u1);
    f = bflo(q1.z); u0 = fmaf(f, w0[12], u0); u1 = fmaf(f, w1[12], u1);
    f = bfhi(q1.z); u0 = fmaf(f, w0[13], u0); u1 = fmaf(f, w1[13], u1);
    f = bflo(q1.w); u0 = fmaf(f, w0[14], u0); u1 = fmaf(f, w1[14], u1);
    f = bfhi(q1.w); u0 = fmaf(f, w0[15], u0); u1 = fmaf(f, w1[15], u1);
    a0 += fmaxf(u0, 0.f);
    a1 += fmaxf(u1, 0.f);
    cnt += 1.f;
    q0 = n0; q1 = n1; g = ng;
  }
  if (cur >= 0) {
    atomicAdd(&esum[cur * 128 + lane], a0);
    atomicAdd(&esum[cur * 128 + 64 + lane], a1);
    if (lane == 0) atomicAdd(&ecnt[cur], cnt);
  }
}

// ---------------- fused dispatch: blocks [0,eb) edge-MLP stream, [eb,grid) SpMM ----------------
__global__ __launch_bounds__(256) void spmm_edge_kernel(const unsigned int* __restrict__ hpk2,
                                                        const float* __restrict__ dinv,
                                                        const int* __restrict__ rp,
                                                        const unsigned int* __restrict__ swp,
                                                        const float* __restrict__ bias,
                                                        float* __restrict__ outp,
                                                        float* __restrict__ bnsum,
                                                        float* __restrict__ bnsq, int nN,
                                                        const unsigned int* __restrict__ eah,
                                                        const unsigned int* __restrict__ epk,
                                                        const float* __restrict__ We1,
                                                        const float* __restrict__ be1,
                                                        float* __restrict__ esum,
                                                        float* __restrict__ ecnt,
                                                        int eoff, int eend, int chunkE,
                                                        int eb) {
  if ((int)blockIdx.x < eb) {
    edge_body(eah, epk, We1, be1, esum, ecnt, eoff, eend, chunkE);
  } else {
    spmm_body(hpk2, dinv, rp, swp, bias, outp, bnsum, bnsq, nN, eb);
  }
}

// ---------------- graph mean pool, BN (from raw stats) + ReLU fused ----------------
__global__ __launch_bounds__(256) void pool_kernel(const float* __restrict__ h,
                                                   const int* __restrict__ batch,
                                                   const float* __restrict__ bs,
                                                   const float* __restrict__ bq,
                                                   const float* __restrict__ gm,
                                                   const float* __restrict__ bt,
                                                   float invN,
                                                   float* __restrict__ gsum,
                                                   float* __restrict__ gcnt,
                                                   int nN, int chunk) {
  const int lane = threadIdx.x & 63;
  const int wid = (blockIdx.x * blockDim.x + threadIdx.x) >> 6;
  int beg = wid * chunk;
  if (beg >= nN) return;
  int end = min(nN, beg + chunk);
  const int c2 = 2 * lane;
  float mu0 = bs[c2] * invN, mu1 = bs[c2 + 1] * invN;
  float va0 = bq[c2] * invN - mu0 * mu0, va1 = bq[c2 + 1] * invN - mu1 * mu1;
  float sc0 = gm[c2] * rsqrtf(va0 + 1e-5f), sc1v = gm[c2 + 1] * rsqrtf(va1 + 1e-5f);
  float sh0 = bt[c2] - mu0 * sc0, sh1v = bt[c2 + 1] - mu1 * sc1v;
  int cur = -1;
  float a0 = 0.f, a1 = 0.f, cnt = 0.f;
  for (int n = beg; n < end; ++n) {
    int g = batch[n];
    if (g != cur) {
      if (cur >= 0) {
        atomicAdd(&gsum[cur * 128 + c2], a0);
        atomicAdd(&gsum[cur * 128 + c2 + 1], a1);
        if (lane == 0) atomicAdd(&gcnt[cur], cnt);
      }
      cur = g; a0 = 0.f; a1 = 0.f; cnt = 0.f;
    }
    float2 v = *reinterpret_cast<const float2*>(h + (size_t)n * 128 + c2);
    a0 += fmaxf(fmaf(v.x, sc0, sh0), 0.f);
    a1 += fmaxf(fmaf(v.y, sc1v, sh1v), 0.f);
    cnt += 1.f;
  }
  if (cur >= 0) {
    atomicAdd(&gsum[cur * 128 + c2], a0);
    atomicAdd(&gsum[cur * 128 + c2 + 1], a1);
    if (lane == 0) atomicAdd(&gcnt[cur], cnt);
  }
}

// ---------------- ea reorder (fallback path when eah aliases bufB) ----------------
__global__ __launch_bounds__(256) void scatter_kernel(const float* __restrict__ ea,
                                                      const int* __restrict__ pos2,
                                                      unsigned int* __restrict__ eah, int nE) {
  int e = blockIdx.x * 256 + threadIdx.x;
  if (e < nE) {
    const float4* p = reinterpret_cast<const float4*>(ea + (size_t)e * 16);
    float4 a = p[0], b = p[1], c = p[2], d = p[3];
    uint4 o0, o1;
    o0.x = bfpack2(a.x, a.y); o0.y = bfpack2(a.z, a.w);
    o0.z = bfpack2(b.x, b.y); o0.w = bfpack2(b.z, b.w);
    o1.x = bfpack2(c.x, c.y); o1.y = bfpack2(c.z, c.w);
    o1.z = bfpack2(d.x, d.y); o1.w = bfpack2(d.z, d.w);
    int j = pos2[e];
    uint4* dst = reinterpret_cast<uint4*>(eah + (size_t)j * 8);
    dst[0] = o0;
    dst[1] = o1;
  }
}

// ---------------- standalone edge kernel (fallback path) ----------------
__global__ __launch_bounds__(256) void edge6_kernel(const unsigned int* __restrict__ eah,
                                                    const unsigned int* __restrict__ epk,
                                                    const float* __restrict__ We1,
                                                    const float* __restrict__ be1,
                                                    float* __restrict__ esum,
                                                    float* __restrict__ ecnt,
                                                    int nE, int chunk) {
  edge_body(eah, epk, We1, be1, esum, ecnt, 0, nE, chunk);
}

// ---------------- final: graph_repr + edge_repr ----------------
__global__ __launch_bounds__(128) void final_kernel(const float* __restrict__ gsum,
                                                    const float* __restrict__ gcnt,
                                                    const float* __restrict__ esum,
                                                    const float* __restrict__ ecnt,
                                                    const float* __restrict__ We2,
                                                    const float* __restrict__ be2,
                                                    float* __restrict__ out) {
  __shared__ float row[128];
  int g = blockIdx.x, c = threadIdx.x;
  row[c] = esum[g * 128 + c];
  __syncthreads();
  float acc = 0.f;
#pragma unroll 4
  for (int k = 0; k < 128; ++k) acc = fmaf(row[k], We2[k * 128 + c], acc);
  float ce = ecnt[g];
  float er = (ce > 0.f) ? (acc / ce + be2[c]) : 0.f;
  float cn = gcnt[g];
  float gr = gsum[g * 128 + c] / fmaxf(cn, 1.f);
  out[g * 128 + c] = gr + er;
}

extern "C" void kernel_launch(void* const* d_in, const int* in_sizes, int n_in,
                              void* d_out, int out_size, void* d_ws, size_t ws_size,
                              hipStream_t stream) {
  const float* x    = (const float*)d_in[0];
  const int*   ei   = (const int*)d_in[1];
  const float* ea   = (const float*)d_in[2];
  const int*   bidx = (const int*)d_in[3];
  const float* Wg1  = (const float*)d_in[4];
  const float* bg1  = (const float*)d_in[5];
  const float* gm1  = (const float*)d_in[6];
  const float* bt1  = (const float*)d_in[7];
  const float* Wg2  = (const float*)d_in[8];
  const float* bg2  = (const float*)d_in[9];
  const float* gm2  = (const float*)d_in[10];
  const float* bt2  = (const float*)d_in[11];
  const float* We1  = (const float*)d_in[12];
  const float* be1  = (const float*)d_in[13];
  const float* We2  = (const float*)d_in[14];
  const float* be2  = (const float*)d_in[15];
  float* out = (float*)d_out;

  const int N = in_sizes[3];
  const int E = in_sizes[1] / 2;
  const int G = out_size / 128;
  const int* srcp = ei;
  const int* dstp = ei + E;
  const int Epad = E + 8 * N;

  char* w = (char*)d_ws;
  auto alloc = [&](size_t b) {
    char* p = w;
    w += (b + 15) & ~(size_t)15;
    return p;
  };
  float* bufB    = (float*)alloc((size_t)N * 128 * 4);            // fp32 spmm output; dead after pool
  unsigned int* hpk2 = (unsigned int*)alloc((size_t)N * 64 * 4);  // packed bf16 h, slice-major
  unsigned int* swp = (unsigned int*)alloc(((size_t)Epad + 32) * 4); // packed {wgt15|src17} + zero tail
  unsigned int* epk = (unsigned int*)alloc((size_t)E * 4);
  int*   pos2    = (int*)alloc((size_t)E * 4);                    // graph-sort rank (fallback path only)
  int*   rp      = (int*)alloc((size_t)(N + 1) * 4);
  int*   rp2     = (int*)alloc((size_t)(N + 1) * 4);
  int*   cursor  = (int*)alloc((size_t)N * 4);
  int*   cursor2 = (int*)alloc((size_t)N * 4);
  float* dinv    = (float*)alloc((size_t)N * 4);
  char* zbase = w;
  int*   deg  = (int*)alloc((size_t)N * 4);
  int*   deg2 = (int*)alloc((size_t)N * 4);
  float* bs1  = (float*)alloc(512);
  float* bq1  = (float*)alloc(512);
  float* bs2  = (float*)alloc(512);
  float* bq2  = (float*)alloc(512);
  float* gsum = (float*)alloc((size_t)G * 128 * 4);
  float* gcnt = (float*)alloc((size_t)G * 4);
  float* esum = (float*)alloc((size_t)G * 128 * 4);
  float* ecnt = (float*)alloc((size_t)G * 4);
  int*   part  = (int*)alloc(4096);
  int*   part2 = (int*)alloc(4096);
  size_t zbytes = (size_t)(w - zbase);

  // Dedicated eah (E x 32B bf16 rows) if workspace permits; else alias bufB
  // (fallback: separate scatter kernel + standalone edge kernel after pool).
  size_t used = (size_t)(w - (char*)d_ws);
  size_t eah_bytes = (size_t)E * 32;
  bool dedicated = (used + eah_bytes + 64) <= ws_size;
  unsigned int* eah = dedicated ? (unsigned int*)alloc(eah_bytes) : (unsigned int*)bufB;

  hipMemsetAsync(zbase, 0, zbytes, stream);

  (void)hipFuncSetAttribute((const void*)gemm128_kernel<false>,
                            hipFuncAttributeMaxDynamicSharedMemorySize, 74752);
  (void)hipFuncSetAttribute((const void*)gemm128_kernel<true>,
                            hipFuncAttributeMaxDynamicSharedMemorySize, 74752);

  // ---- prep ----
  pre_kernel<<<(E + 255) / 256, 256, 0, stream>>>(srcp, dstp, deg, deg2, E);
  int nb = (N + 1023) / 1024;
  scanA_kernel<<<2 * nb, 256, 0, stream>>>(deg, deg2, rp, rp2, part, part2, N, nb);
  scanB_kernel<<<2, 64, 0, stream>>>(part, part2, rp, rp2, nb, N);
  scanC_kernel<<<(2 * N + 255) / 256, 256, 0, stream>>>(rp, rp2, part, part2, cursor,
                                                        cursor2, deg, dinv, N);
  int ppg = (E + N + 32 + 255) / 256;
  if (dedicated) {
    placepad_kernel<true><<<ppg, 256, 0, stream>>>(srcp, dstp, bidx, dinv, ea, cursor,
                                                   cursor2, swp, epk, pos2, eah, rp, deg,
                                                   E, N);
  } else {
    placepad_kernel<false><<<ppg, 256, 0, stream>>>(srcp, dstp, bidx, dinv, ea, cursor,
                                                    cursor2, swp, epk, pos2, eah, rp, deg,
                                                    E, N);
  }

  const float invN = 1.0f / (float)N;
  const int EB = dedicated ? 256 : 0;   // edge-stream blocks co-scheduled with spmm
  const int Ehalf = E / 2;
  int chunkE1 = EB ? (Ehalf + EB * 4 - 1) / (EB * 4) : 1;
  int chunkE2 = EB ? ((E - Ehalf) + EB * 4 - 1) / (EB * 4) : 1;

  // layer 1 (edge stream first half rides along)
  gemm128_kernel<false><<<512, 256, 74752, stream>>>(x, Wg1, nullptr, nullptr, nullptr,
                                                     nullptr, 0.f, hpk2, N);
  spmm_edge_kernel<<<EB + 2048, 256, 0, stream>>>(hpk2, dinv, rp, swp, bg1, bufB, bs1, bq1,
                                                  N, eah, epk, We1, be1, esum, ecnt,
                                                  0, EB ? Ehalf : 0, chunkE1, EB);

  // layer 2 (BN1 fused into GEMM2's A staging; edge stream second half rides along)
  gemm128_kernel<true><<<512, 256, 74752, stream>>>(bufB, Wg2, bs1, bq1, gm1, bt1, invN,
                                                    hpk2, N);
  spmm_edge_kernel<<<EB + 2048, 256, 0, stream>>>(hpk2, dinv, rp, swp, bg2, bufB, bs2, bq2,
                                                  N, eah, epk, We1, be1, esum, ecnt,
                                                  Ehalf, EB ? E : 0, chunkE2, EB);

  // pooling (BN2 finalize + apply + ReLU fused) -- last reader of bufB
  int nwp = (2048 * 256) / 64;
  int chunkN = (N + nwp - 1) / nwp;
  pool_kernel<<<2048, 256, 0, stream>>>(bufB, bidx, bs2, bq2, gm2, bt2, invN,
                                        gsum, gcnt, N, chunkN);

  // fallback edge path (eah aliased bufB; must run after pool)
  if (!dedicated) {
    scatter_kernel<<<(E + 255) / 256, 256, 0, stream>>>(ea, pos2, eah, E);
    int nwe = (2048 * 256) / 64;
    int chunkE = (E + nwe - 1) / nwe;
    edge6_kernel<<<2048, 256, 0, stream>>>(eah, epk, We1, be1, esum, ecnt, E, chunkE);
  }

  final_kernel<<<G, 128, 0, stream>>>(gsum, gcnt, esum, ecnt, We2, be2, out);
}

// Round 17
// 1225.866 us; speedup vs baseline: 1.1158x; 1.1158x over previous
//
#include <hip/hip_runtime.h>
#include <cstdint>

// ---- bf16 pack/unpack helpers (RNE) ----
__device__ inline unsigned int bfpack2(float a, float b) {
  unsigned int ua = __float_as_uint(a), ub = __float_as_uint(b);
  ua += 0x7FFFu + ((ua >> 16) & 1u);
  ub += 0x7FFFu + ((ub >> 16) & 1u);
  return (ua >> 16) | (ub & 0xFFFF0000u);
}
__device__ inline float bflo(unsigned int u) { return __uint_as_float(u << 16); }
__device__ inline float bfhi(unsigned int u) { return __uint_as_float(u & 0xFFFF0000u); }

// ---------------- degree histograms ----------------
__global__ __launch_bounds__(256) void pre_kernel(const int* __restrict__ src,
                                                  const int* __restrict__ dst,
                                                  int* __restrict__ deg,
                                                  int* __restrict__ deg2, int nE) {
  int e = blockIdx.x * 256 + threadIdx.x;
  if (e < nE) {
    atomicAdd(&deg[dst[e]], 1);
    atomicAdd(&deg2[src[e]], 1);
  }
}

// ---------------- scan stage A (dual; deg gets 8-pad rounding) ----------------
__global__ __launch_bounds__(256) void scanA_kernel(const int* __restrict__ deg,
                                                    const int* __restrict__ deg2,
                                                    int* __restrict__ rp,
                                                    int* __restrict__ rp2,
                                                    int* __restrict__ part,
                                                    int* __restrict__ part2,
                                                    int n, int nb) {
  __shared__ int sh[256];
  int b = blockIdx.x, t = threadIdx.x;
  const int* d = (b < nb) ? deg : deg2;
  int* r = (b < nb) ? rp : rp2;
  int* p = (b < nb) ? part : part2;
  int pad = (b < nb) ? 1 : 0;
  int bb = (b < nb) ? b : b - nb;
  int base = bb * 1024 + t * 4;
  int v0 = (base + 0 < n) ? d[base + 0] : 0;
  int v1 = (base + 1 < n) ? d[base + 1] : 0;
  int v2 = (base + 2 < n) ? d[base + 2] : 0;
  int v3 = (base + 3 < n) ? d[base + 3] : 0;
  if (pad) {
    v0 = (v0 + 7) & ~7; v1 = (v1 + 7) & ~7;
    v2 = (v2 + 7) & ~7; v3 = (v3 + 7) & ~7;
  }
  int ts = v0 + v1 + v2 + v3;
  sh[t] = ts;
  __syncthreads();
  for (int off = 1; off < 256; off <<= 1) {
    int x = (t >= off) ? sh[t - off] : 0;
    __syncthreads();
    sh[t] += x;
    __syncthreads();
  }
  int excl = sh[t] - ts;
  if (t == 255) p[bb] = sh[255];
  if (base + 0 < n) r[base + 0] = excl;
  if (base + 1 < n) r[base + 1] = excl + v0;
  if (base + 2 < n) r[base + 2] = excl + v0 + v1;
  if (base + 3 < n) r[base + 3] = excl + v0 + v1 + v2;
}

__global__ void scanB_kernel(int* part, int* part2, int* rp, int* rp2, int nb, int n) {
  if (threadIdx.x == 0) {
    int* p = (blockIdx.x == 0) ? part : part2;
    int* r = (blockIdx.x == 0) ? rp : rp2;
    int run = 0;
    for (int i = 0; i < nb; ++i) { int v = p[i]; p[i] = run; run += v; }
    r[n] = run;
  }
}

__global__ __launch_bounds__(256) void scanC_kernel(int* __restrict__ rp,
                                                    int* __restrict__ rp2,
                                                    const int* __restrict__ part,
                                                    const int* __restrict__ part2,
                                                    int* __restrict__ cursor,
                                                    int* __restrict__ cursor2,
                                                    const int* __restrict__ deg,
                                                    float* __restrict__ dinv, int n) {
  int i = blockIdx.x * 256 + threadIdx.x;
  if (i < n) {
    int v = rp[i] + part[i >> 10];
    rp[i] = v;
    cursor[i] = v;
    dinv[i] = rsqrtf((float)deg[i] + 1.0f);
  } else if (i < 2 * n) {
    int j = i - n;
    int v = rp2[j] + part2[j >> 10];
    rp2[j] = v;
    cursor2[j] = v;
  }
}

// ---------------- place + pad fused ----------------
// swp entry: (wgt as sign-less bf16, 15b) << 17 | src (17b).  wgt in (0,1] so
// the bf16 sign bit is always 0 and 15 bits suffice.  Pad/tail entries have
// wgt bits 0 -> contribute nothing.
// SC=true: also packs ea row to bf16 and scatters to eah[p2] inline.
template <bool SC>
__global__ __launch_bounds__(256) void placepad_kernel(const int* __restrict__ src,
                                                       const int* __restrict__ dst,
                                                       const int* __restrict__ batch,
                                                       const float* __restrict__ dinv,
                                                       const float* __restrict__ ea,
                                                       int* __restrict__ cursor,
                                                       int* __restrict__ cursor2,
                                                       unsigned int* __restrict__ swp,
                                                       unsigned int* __restrict__ epk,
                                                       int* __restrict__ pos2,
                                                       unsigned int* __restrict__ eah,
                                                       const int* __restrict__ rp,
                                                       const int* __restrict__ deg,
                                                       int nE, int nN) {
  int t = blockIdx.x * 256 + threadIdx.x;
  if (t < nE) {
    int s = src[t];
    int d = dst[t];
    int p1 = atomicAdd(&cursor[d], 1);
    unsigned int fb = __float_as_uint(dinv[s] * dinv[d]);
    fb += 0x7FFFu + ((fb >> 16) & 1u);
    swp[p1] = ((fb >> 16) << 17) | (unsigned int)s;
    int g = batch[s];
    int p2 = atomicAdd(&cursor2[s], 1);
    epk[p2] = ((unsigned int)g << 21) | (unsigned int)t;
    if (SC) {
      const float4* p = reinterpret_cast<const float4*>(ea + (size_t)t * 16);
      float4 a = p[0], b = p[1], c = p[2], dd = p[3];
      uint4 o0, o1;
      o0.x = bfpack2(a.x, a.y); o0.y = bfpack2(a.z, a.w);
      o0.z = bfpack2(b.x, b.y); o0.w = bfpack2(b.z, b.w);
      o1.x = bfpack2(c.x, c.y); o1.y = bfpack2(c.z, c.w);
      o1.z = bfpack2(dd.x, dd.y); o1.w = bfpack2(dd.z, dd.w);
      uint4* dp = reinterpret_cast<uint4*>(eah + (size_t)p2 * 8);
      dp[0] = o0;
      dp[1] = o1;
    } else {
      pos2[t] = p2;
    }
  } else if (t < nE + nN) {
    int i = t - nE;
    int b = rp[i] + deg[i], e = rp[i + 1];
    for (int k = b; k < e; ++k) swp[k] = (unsigned int)i;  // wgt bits 0
  } else if (t < nE + nN + 32) {
    int k = t - nE - nN;
    swp[rp[nN] + k] = 0u;
  }
}

// ---------------- dense GEMM: hpk2[8][N][8] = pack_bf16(act(A) @ W), slice-major ----------------
template <bool FUSED>
__global__ __launch_bounds__(256) void gemm128_kernel(const float* __restrict__ A,
                                                      const float* __restrict__ W,
                                                      const float* __restrict__ bs,
                                                      const float* __restrict__ bq,
                                                      const float* __restrict__ gm,
                                                      const float* __restrict__ bt,
                                                      float invN,
                                                      unsigned int* __restrict__ hpk2,
                                                      int nrows) {
  extern __shared__ float lds[];
  float* Ws = lds;                      // 128*128
  float* xs = lds + 128 * 128;          // 16*128
  float* scs = xs + 16 * 128;           // 128
  float* shs = scs + 128;               // 128
  const int t = threadIdx.x;
  for (int i = t; i < (128 * 128) / 4; i += 256)
    reinterpret_cast<float4*>(Ws)[i] = reinterpret_cast<const float4*>(W)[i];
  if (FUSED && t < 128) {
    float mu = bs[t] * invN;
    float var = bq[t] * invN - mu * mu;
    float sc = gm[t] * rsqrtf(var + 1e-5f);
    scs[t] = sc;
    shs[t] = bt[t] - mu * sc;
  }
  const int wave = t >> 6, lane = t & 63;
  const size_t sbase = (size_t)(lane >> 3) * (size_t)nrows * 8 + (lane & 7);
  for (int rb = blockIdx.x * 16; rb < nrows; rb += gridDim.x * 16) {
    int nr = min(16, nrows - rb);
    __syncthreads();
    for (int i = t; i < nr * 32; i += 256) {
      float4 v = reinterpret_cast<const float4*>(A + (size_t)rb * 128)[i];
      if (FUSED) {
        float4 sc4 = reinterpret_cast<const float4*>(scs)[i & 31];
        float4 sh4 = reinterpret_cast<const float4*>(shs)[i & 31];
        v.x = fmaxf(fmaf(v.x, sc4.x, sh4.x), 0.f);
        v.y = fmaxf(fmaf(v.y, sc4.y, sh4.y), 0.f);
        v.z = fmaxf(fmaf(v.z, sc4.z, sh4.z), 0.f);
        v.w = fmaxf(fmaf(v.w, sc4.w, sh4.w), 0.f);
      }
      reinterpret_cast<float4*>(xs)[i] = v;
    }
    __syncthreads();
    float acc[4][2] = {{0.f, 0.f}, {0.f, 0.f}, {0.f, 0.f}, {0.f, 0.f}};
    const float* xw = xs + wave * 4 * 128;
#pragma unroll 4
    for (int k = 0; k < 128; ++k) {
      float w0 = Ws[k * 128 + lane];
      float w1 = Ws[k * 128 + 64 + lane];
#pragma unroll
      for (int r = 0; r < 4; ++r) {
        float a = xw[r * 128 + k];
        acc[r][0] = fmaf(a, w0, acc[r][0]);
        acc[r][1] = fmaf(a, w1, acc[r][1]);
      }
    }
#pragma unroll
    for (int r = 0; r < 4; ++r) {
      int row = rb + wave * 4 + r;
      if (row < nrows)
        hpk2[sbase + (size_t)row * 8] = bfpack2(acc[r][0], acc[r][1]);
    }
  }
}

// ---------------- SpMM, XCD channel-sliced, TWO nodes per wave ----------------
// 4B packed index+weight (u32): halves the per-slice index stream that all 8
// slices redundantly read.
__global__ __launch_bounds__(256) void spmm8_kernel(const unsigned int* __restrict__ hpk2,
                                                    const float* __restrict__ dinv,
                                                    const int* __restrict__ rp,
                                                    const unsigned int* __restrict__ swp,
                                                    const float* __restrict__ bias,
                                                    float* __restrict__ outp,
                                                    float* __restrict__ bnsum,
                                                    float* __restrict__ bnsq, int nN) {
  const int lane = threadIdx.x & 63;
  const int ch = lane & 7;
  const int es = lane >> 3;
  const int slice = blockIdx.x & 7;
  const unsigned int* hs = hpk2 + (size_t)slice * (size_t)nN * 8;
  const int cb = slice * 8;
  const int wib = (int)(blockIdx.x >> 3) * 4 + (int)(threadIdx.x >> 6);
  const int nws = (int)(gridDim.x >> 3) * 4;
  float b0 = bias[cb + ch], b1 = bias[64 + cb + ch];
  float s0 = 0.f, s1 = 0.f, q0 = 0.f, q1 = 0.f;
  const int half = (nN + 1) >> 1;

#define SPMM_CHUNK(J, ACC0, ACC1)                                         \
  {                                                                       \
    unsigned int v_ = __builtin_nontemporal_load(swp + (J) + es);         \
    unsigned int pp_ = hs[(size_t)(v_ & 0x1FFFFu) * 8 + ch];              \
    float ww_ = __uint_as_float((v_ & 0xFFFE0000u) >> 1);                 \
    ACC0 = fmaf(ww_, bflo(pp_), ACC0);                                    \
    ACC1 = fmaf(ww_, bfhi(pp_), ACC1);                                    \
  }

  for (int p = wib; p < half; p += nws) {
    const int n0 = p;
    const int n1 = p + half;
    const bool has1 = n1 < nN;
    int j0 = rp[n0];
    const int end0 = rp[n0 + 1];
    int j1 = 0, end1 = 0;
    if (has1) { j1 = rp[n1]; end1 = rp[n1 + 1]; }
    float a00 = 0.f, a01 = 0.f, b00 = 0.f, b01 = 0.f;
    float a10 = 0.f, a11 = 0.f, b10 = 0.f, b11 = 0.f;
    while (j0 + 8 < end0 && j1 + 8 < end1) {
      SPMM_CHUNK(j0, a00, a01);
      SPMM_CHUNK(j0 + 8, b00, b01);
      SPMM_CHUNK(j1, a10, a11);
      SPMM_CHUNK(j1 + 8, b10, b11);
      j0 += 16; j1 += 16;
    }
    while (j0 + 8 < end0) {
      SPMM_CHUNK(j0, a00, a01);
      SPMM_CHUNK(j0 + 8, b00, b01);
      j0 += 16;
    }
    if (j0 < end0) SPMM_CHUNK(j0, a00, a01);
    while (j1 + 8 < end1) {
      SPMM_CHUNK(j1, a10, a11);
      SPMM_CHUNK(j1 + 8, b10, b11);
      j1 += 16;
    }
    if (j1 < end1) SPMM_CHUNK(j1, a10, a11);

    a00 += b00; a01 += b01;
    a10 += b10; a11 += b11;
    a00 += __shfl_xor(a00, 8);  a01 += __shfl_xor(a01, 8);
    a10 += __shfl_xor(a10, 8);  a11 += __shfl_xor(a11, 8);
    a00 += __shfl_xor(a00, 16); a01 += __shfl_xor(a01, 16);
    a10 += __shfl_xor(a10, 16); a11 += __shfl_xor(a11, 16);
    a00 += __shfl_xor(a00, 32); a01 += __shfl_xor(a01, 32);
    a10 += __shfl_xor(a10, 32); a11 += __shfl_xor(a11, 32);
    if (es == 0) {
      {
        float dn = dinv[n0];
        float sw = dn * dn;
        unsigned int pn = hs[(size_t)n0 * 8 + ch];
        float o0 = fmaf(bflo(pn), sw, a00) + b0;
        float o1 = fmaf(bfhi(pn), sw, a01) + b1;
        __builtin_nontemporal_store(o0, &outp[(size_t)n0 * 128 + cb + ch]);
        __builtin_nontemporal_store(o1, &outp[(size_t)n0 * 128 + 64 + cb + ch]);
        s0 += o0; s1 += o1;
        q0 = fmaf(o0, o0, q0); q1 = fmaf(o1, o1, q1);
      }
      if (has1) {
        float dn = dinv[n1];
        float sw = dn * dn;
        unsigned int pn = hs[(size_t)n1 * 8 + ch];
        float o0 = fmaf(bflo(pn), sw, a10) + b0;
        float o1 = fmaf(bfhi(pn), sw, a11) + b1;
        __builtin_nontemporal_store(o0, &outp[(size_t)n1 * 128 + cb + ch]);
        __builtin_nontemporal_store(o1, &outp[(size_t)n1 * 128 + 64 + cb + ch]);
        s0 += o0; s1 += o1;
        q0 = fmaf(o0, o0, q0); q1 = fmaf(o1, o1, q1);
      }
    }
  }
#undef SPMM_CHUNK
  if (es == 0) {
    atomicAdd(&bnsum[cb + ch], s0);
    atomicAdd(&bnsum[64 + cb + ch], s1);
    atomicAdd(&bnsq[cb + ch], q0);
    atomicAdd(&bnsq[64 + cb + ch], q1);
  }
}

// ---------------- graph mean pool, BN (from raw stats) + ReLU fused ----------------
__global__ __launch_bounds__(256) void pool_kernel(const float* __restrict__ h,
                                                   const int* __restrict__ batch,
                                                   const float* __restrict__ bs,
                                                   const float* __restrict__ bq,
                                                   const float* __restrict__ gm,
                                                   const float* __restrict__ bt,
                                                   float invN,
                                                   float* __restrict__ gsum,
                                                   float* __restrict__ gcnt,
                                                   int nN, int chunk) {
  const int lane = threadIdx.x & 63;
  const int wid = (blockIdx.x * blockDim.x + threadIdx.x) >> 6;
  int beg = wid * chunk;
  if (beg >= nN) return;
  int end = min(nN, beg + chunk);
  const int c2 = 2 * lane;
  float mu0 = bs[c2] * invN, mu1 = bs[c2 + 1] * invN;
  float va0 = bq[c2] * invN - mu0 * mu0, va1 = bq[c2 + 1] * invN - mu1 * mu1;
  float sc0 = gm[c2] * rsqrtf(va0 + 1e-5f), sc1v = gm[c2 + 1] * rsqrtf(va1 + 1e-5f);
  float sh0 = bt[c2] - mu0 * sc0, sh1v = bt[c2 + 1] - mu1 * sc1v;
  int cur = -1;
  float a0 = 0.f, a1 = 0.f, cnt = 0.f;
  for (int n = beg; n < end; ++n) {
    int g = batch[n];
    if (g != cur) {
      if (cur >= 0) {
        atomicAdd(&gsum[cur * 128 + c2], a0);
        atomicAdd(&gsum[cur * 128 + c2 + 1], a1);
        if (lane == 0) atomicAdd(&gcnt[cur], cnt);
      }
      cur = g; a0 = 0.f; a1 = 0.f; cnt = 0.f;
    }
    float2 v = *reinterpret_cast<const float2*>(h + (size_t)n * 128 + c2);
    a0 += fmaxf(fmaf(v.x, sc0, sh0), 0.f);
    a1 += fmaxf(fmaf(v.y, sc1v, sh1v), 0.f);
    cnt += 1.f;
  }
  if (cur >= 0) {
    atomicAdd(&gsum[cur * 128 + c2], a0);
    atomicAdd(&gsum[cur * 128 + c2 + 1], a1);
    if (lane == 0) atomicAdd(&gcnt[cur], cnt);
  }
}

// ---------------- ea reorder (fallback path when eah aliases bufB) ----------------
__global__ __launch_bounds__(256) void scatter_kernel(const float* __restrict__ ea,
                                                      const int* __restrict__ pos2,
                                                      unsigned int* __restrict__ eah, int nE) {
  int e = blockIdx.x * 256 + threadIdx.x;
  if (e < nE) {
    const float4* p = reinterpret_cast<const float4*>(ea + (size_t)e * 16);
    float4 a = p[0], b = p[1], c = p[2], d = p[3];
    uint4 o0, o1;
    o0.x = bfpack2(a.x, a.y); o0.y = bfpack2(a.z, a.w);
    o0.z = bfpack2(b.x, b.y); o0.w = bfpack2(b.z, b.w);
    o1.x = bfpack2(c.x, c.y); o1.y = bfpack2(c.z, c.w);
    o1.z = bfpack2(d.x, d.y); o1.w = bfpack2(d.z, d.w);
    int j = pos2[e];
    uint4* dst = reinterpret_cast<uint4*>(eah + (size_t)j * 8);
    dst[0] = o0;
    dst[1] = o1;
  }
}

// ---------------- edge MLP: STREAM graph-sorted bf16 rows, run-length regs ----------------
__global__ __launch_bounds__(256) void edge6_kernel(const unsigned int* __restrict__ eah,
                                                    const unsigned int* __restrict__ epk,
                                                    const float* __restrict__ We1,
                                                    const float* __restrict__ be1,
                                                    float* __restrict__ esum,
                                                    float* __restrict__ ecnt,
                                                    int nE, int chunk) {
  const int lane = threadIdx.x & 63;
  const int wid = (blockIdx.x * 256 + threadIdx.x) >> 6;
  int beg = wid * chunk;
  if (beg >= nE) return;
  int end = min(nE, beg + chunk);
  float w0[16], w1[16];
#pragma unroll
  for (int k = 0; k < 16; ++k) {
    w0[k] = We1[k * 128 + lane];
    w1[k] = We1[k * 128 + 64 + lane];
  }
  float b0 = be1[lane], b1 = be1[64 + lane];
  int cur = -1;
  float a0 = 0.f, a1 = 0.f, cnt = 0.f;
  const uint4* rowp = reinterpret_cast<const uint4*>(eah + (size_t)beg * 8);
  uint4 q0 = rowp[0], q1 = rowp[1];
  int g = (int)(epk[beg] >> 21);
  for (int j = beg; j < end; ++j) {
    uint4 n0, n1;
    int ng = g;
    if (j + 1 < end) {
      const uint4* np = reinterpret_cast<const uint4*>(eah + (size_t)(j + 1) * 8);
      n0 = np[0];
      n1 = np[1];
      ng = (int)(epk[j + 1] >> 21);
    }
    if (g != cur) {
      if (cur >= 0) {
        atomicAdd(&esum[cur * 128 + lane], a0);
        atomicAdd(&esum[cur * 128 + 64 + lane], a1);
        if (lane == 0) atomicAdd(&ecnt[cur], cnt);
      }
      cur = g; a0 = 0.f; a1 = 0.f; cnt = 0.f;
    }
    float u0 = b0, u1 = b1;
    float f;
    f = bflo(q0.x); u0 = fmaf(f, w0[0], u0);  u1 = fmaf(f, w1[0], u1);
    f = bfhi(q0.x); u0 = fmaf(f, w0[1], u0);  u1 = fmaf(f, w1[1], u1);
    f = bflo(q0.y); u0 = fmaf(f, w0[2], u0);  u1 = fmaf(f, w1[2], u1);
    f = bfhi(q0.y); u0 = fmaf(f, w0[3], u0);  u1 = fmaf(f, w1[3], u1);
    f = bflo(q0.z); u0 = fmaf(f, w0[4], u0);  u1 = fmaf(f, w1[4], u1);
    f = bfhi(q0.z); u0 = fmaf(f, w0[5], u0);  u1 = fmaf(f, w1[5], u1);
    f = bflo(q0.w); u0 = fmaf(f, w0[6], u0);  u1 = fmaf(f, w1[6], u1);
    f = bfhi(q0.w); u0 = fmaf(f, w0[7], u0);  u1 = fmaf(f, w1[7], u1);
    f = bflo(q1.x); u0 = fmaf(f, w0[8], u0);  u1 = fmaf(f, w1[8], u1);
    f = bfhi(q1.x); u0 = fmaf(f, w0[9], u0);  u1 = fmaf(f, w1[9], u1);
    f = bflo(q1.y); u0 = fmaf(f, w0[10], u0); u1 = fmaf(f, w1[10], u1);
    f = bfhi(q1.y); u0 = fmaf(f, w0[11], u0); u1 = fmaf(f, w1[11], u1);
    f = bflo(q1.z); u0 = fmaf(f, w0[12], u0); u1 = fmaf(f, w1[12], u1);
    f = bfhi(q1.z); u0 = fmaf(f, w0[13], u0); u1 = fmaf(f, w1[13], u1);
    f = bflo(q1.w); u0 = fmaf(f, w0[14], u0); u1 = fmaf(f, w1[14], u1);
    f = bfhi(q1.w); u0 = fmaf(f, w0[15], u0); u1 = fmaf(f, w1[15], u1);
    a0 += fmaxf(u0, 0.f);
    a1 += fmaxf(u1, 0.f);
    cnt += 1.f;
    q0 = n0; q1 = n1; g = ng;
  }
  if (cur >= 0) {
    atomicAdd(&esum[cur * 128 + lane], a0);
    atomicAdd(&esum[cur * 128 + 64 + lane], a1);
    if (lane == 0) atomicAdd(&ecnt[cur], cnt);
  }
}

// ---------------- final: graph_repr + edge_repr ----------------
__global__ __launch_bounds__(128) void final_kernel(const float* __restrict__ gsum,
                                                    const float* __restrict__ gcnt,
                                                    const float* __restrict__ esum,
                                                    const float* __restrict__ ecnt,
                                                    const float* __restrict__ We2,
                                                    const float* __restrict__ be2,
                                                    float* __restrict__ out) {
  __shared__ float row[128];
  int g = blockIdx.x, c = threadIdx.x;
  row[c] = esum[g * 128 + c];
  __syncthreads();
  float acc = 0.f;
#pragma unroll 4
  for (int k = 0; k < 128; ++k) acc = fmaf(row[k], We2[k * 128 + c], acc);
  float ce = ecnt[g];
  float er = (ce > 0.f) ? (acc / ce + be2[c]) : 0.f;
  float cn = gcnt[g];
  float gr = gsum[g * 128 + c] / fmaxf(cn, 1.f);
  out[g * 128 + c] = gr + er;
}

extern "C" void kernel_launch(void* const* d_in, const int* in_sizes, int n_in,
                              void* d_out, int out_size, void* d_ws, size_t ws_size,
                              hipStream_t stream) {
  const float* x    = (const float*)d_in[0];
  const int*   ei   = (const int*)d_in[1];
  const float* ea   = (const float*)d_in[2];
  const int*   bidx = (const int*)d_in[3];
  const float* Wg1  = (const float*)d_in[4];
  const float* bg1  = (const float*)d_in[5];
  const float* gm1  = (const float*)d_in[6];
  const float* bt1  = (const float*)d_in[7];
  const float* Wg2  = (const float*)d_in[8];
  const float* bg2  = (const float*)d_in[9];
  const float* gm2  = (const float*)d_in[10];
  const float* bt2  = (const float*)d_in[11];
  const float* We1  = (const float*)d_in[12];
  const float* be1  = (const float*)d_in[13];
  const float* We2  = (const float*)d_in[14];
  const float* be2  = (const float*)d_in[15];
  float* out = (float*)d_out;

  const int N = in_sizes[3];
  const int E = in_sizes[1] / 2;
  const int G = out_size / 128;
  const int* srcp = ei;
  const int* dstp = ei + E;
  const int Epad = E + 8 * N;

  char* w = (char*)d_ws;
  auto alloc = [&](size_t b) {
    char* p = w;
    w += (b + 15) & ~(size_t)15;
    return p;
  };
  float* bufB    = (float*)alloc((size_t)N * 128 * 4);            // fp32 spmm output; dead after pool
  unsigned int* hpk2 = (unsigned int*)alloc((size_t)N * 64 * 4);  // packed bf16 h, slice-major
  unsigned int* swp = (unsigned int*)alloc(((size_t)Epad + 32) * 4); // packed {wgt15|src17} + zero tail
  unsigned int* epk = (unsigned int*)alloc((size_t)E * 4);
  int*   pos2    = (int*)alloc((size_t)E * 4);                    // graph-sort rank (fallback path only)
  int*   rp      = (int*)alloc((size_t)(N + 1) * 4);
  int*   rp2     = (int*)alloc((size_t)(N + 1) * 4);
  int*   cursor  = (int*)alloc((size_t)N * 4);
  int*   cursor2 = (int*)alloc((size_t)N * 4);
  float* dinv    = (float*)alloc((size_t)N * 4);
  char* zbase = w;
  int*   deg  = (int*)alloc((size_t)N * 4);
  int*   deg2 = (int*)alloc((size_t)N * 4);
  float* bs1  = (float*)alloc(512);
  float* bq1  = (float*)alloc(512);
  float* bs2  = (float*)alloc(512);
  float* bq2  = (float*)alloc(512);
  float* gsum = (float*)alloc((size_t)G * 128 * 4);
  float* gcnt = (float*)alloc((size_t)G * 4);
  float* esum = (float*)alloc((size_t)G * 128 * 4);
  float* ecnt = (float*)alloc((size_t)G * 4);
  int*   part  = (int*)alloc(4096);
  int*   part2 = (int*)alloc(4096);
  size_t zbytes = (size_t)(w - zbase);

  // Dedicated eah (E x 32B bf16 rows) if workspace permits; else alias bufB
  // (fallback: separate scatter kernel after pool).
  size_t used = (size_t)(w - (char*)d_ws);
  size_t eah_bytes = (size_t)E * 32;
  bool dedicated = (used + eah_bytes + 64) <= ws_size;
  unsigned int* eah = dedicated ? (unsigned int*)alloc(eah_bytes) : (unsigned int*)bufB;

  hipMemsetAsync(zbase, 0, zbytes, stream);

  (void)hipFuncSetAttribute((const void*)gemm128_kernel<false>,
                            hipFuncAttributeMaxDynamicSharedMemorySize, 74752);
  (void)hipFuncSetAttribute((const void*)gemm128_kernel<true>,
                            hipFuncAttributeMaxDynamicSharedMemorySize, 74752);

  // ---- prep ----
  pre_kernel<<<(E + 255) / 256, 256, 0, stream>>>(srcp, dstp, deg, deg2, E);
  int nb = (N + 1023) / 1024;
  scanA_kernel<<<2 * nb, 256, 0, stream>>>(deg, deg2, rp, rp2, part, part2, N, nb);
  scanB_kernel<<<2, 64, 0, stream>>>(part, part2, rp, rp2, nb, N);
  scanC_kernel<<<(2 * N + 255) / 256, 256, 0, stream>>>(rp, rp2, part, part2, cursor,
                                                        cursor2, deg, dinv, N);
  int ppg = (E + N + 32 + 255) / 256;
  if (dedicated) {
    placepad_kernel<true><<<ppg, 256, 0, stream>>>(srcp, dstp, bidx, dinv, ea, cursor,
                                                   cursor2, swp, epk, pos2, eah, rp, deg,
                                                   E, N);
  } else {
    placepad_kernel<false><<<ppg, 256, 0, stream>>>(srcp, dstp, bidx, dinv, ea, cursor,
                                                    cursor2, swp, epk, pos2, eah, rp, deg,
                                                    E, N);
  }

  const float invN = 1.0f / (float)N;

  // layer 1
  gemm128_kernel<false><<<512, 256, 74752, stream>>>(x, Wg1, nullptr, nullptr, nullptr,
                                                     nullptr, 0.f, hpk2, N);
  spmm8_kernel<<<2048, 256, 0, stream>>>(hpk2, dinv, rp, swp, bg1, bufB, bs1, bq1, N);

  // layer 2 (BN1 finalize + apply + ReLU fused into GEMM2's A staging)
  gemm128_kernel<true><<<512, 256, 74752, stream>>>(bufB, Wg2, bs1, bq1, gm1, bt1, invN,
                                                    hpk2, N);
  spmm8_kernel<<<2048, 256, 0, stream>>>(hpk2, dinv, rp, swp, bg2, bufB, bs2, bq2, N);

  // pooling (BN2 finalize + apply + ReLU fused) -- last reader of bufB
  int nwp = (2048 * 256) / 64;
  int chunkN = (N + nwp - 1) / nwp;
  pool_kernel<<<2048, 256, 0, stream>>>(bufB, bidx, bs2, bq2, gm2, bt2, invN,
                                        gsum, gcnt, N, chunkN);

  // edge path
  if (!dedicated) {
    scatter_kernel<<<(E + 255) / 256, 256, 0, stream>>>(ea, pos2, eah, E);
  }
  int nwe = (2048 * 256) / 64;
  int chunkE = (E + nwe - 1) / nwe;
  edge6_kernel<<<2048, 256, 0, stream>>>(eah, epk, We1, be1, esum, ecnt, E, chunkE);

  final_kernel<<<G, 128, 0, stream>>>(gsum, gcnt, esum, ecnt, We2, be2, out);
}